// Round 4
// baseline (832.618 us; speedup 1.0000x reference)
//
#include <hip/hip_runtime.h>

// Hodgkin-Huxley synaptic network, Crank-Nicolson integration.
// R4: 2 chains per thread (fills dep-chain stalls), transcendental diet:
//   - sigmoid exp = e1^3 * e^-15  (output-only path, exact algebra)
//   - 1/(1+sN), 1/(1+sy) via 3-fma series (s <= 0.028, err <= 6e-7)
// Per chain per step: 4 exp + 6 rcp (was 5 exp + 8 rcp).
// 2048 threads = 32 waves; 4-deep z prefetch per stream (covers HBM latency).

__device__ __forceinline__ float rcpf(float x) { return __builtin_amdgcn_rcpf(x); }
__device__ __forceinline__ float ex2(float x) { return exp2f(x); }
// 1/(1+s) for small s: 1 - s + s^2 - s^3, err ~ s^4
__device__ __forceinline__ float rcp1p_small(float s) {
    float a = 1.0f - s;
    float b = __builtin_fmaf(-s, a, 1.0f);
    return __builtin_fmaf(-s, b, 1.0f);
}

__device__ __forceinline__ float hh_step(float& V, float& m, float& n, float& h,
                                         float& y, float zc) {
    // ---- membrane ----  (GNA*DT/2 == 1 exactly)
    float m2 = m * m, mh = m * h;
    float p1 = m2 * mh;                          // m^3 h
    float n2 = n * n, n4 = n2 * n2;
    float gy = __builtin_fmaf(0.0125f, y, 0.0025f);
    float pg = p1 + gy;
    float G  = __builtin_fmaf(0.875f, n4, pg);
    float rd = rcpf(G + 1.0f);
    float t1 = __builtin_fmaf(110.0f, p1, V - 0.3f);
    float t2 = __builtin_fmaf(-134.75f, n4, t1);
    float num = __builtin_fmaf(-V, G, t2);       // V*(1-G) + DT*(E+IAPP)
    float Vn = num * rd;

    // ---- N gate ----  e1 = exp((25-Vn)/9) as exp2
    float e1 = ex2(__builtin_fmaf(-0.16025096018360795f, Vn, 4.006274004590199f));
    float r1 = rcpf(1.0f - e1);
    float aN = __builtin_fmaf(0.02f, Vn, -0.5f) * r1;
    float sN = aN * __builtin_fmaf(0.0025f, e1, 0.025f);
    if (Vn == 25.0f) { aN = 0.18f; sN = 0.0065f; }
    n = __builtin_fmaf(0.05f, aN, __builtin_fmaf(-sN, n, n)) * rcp1p_small(sN);

    // ---- M gate ----  e2 = exp((-35-Vn)/9)
    float e2 = ex2(__builtin_fmaf(-0.16025096018360795f, Vn, -5.608783606426278f));
    float r2 = rcpf(1.0f - e2);
    float aM = __builtin_fmaf(0.182f, Vn, 6.37f) * r2;
    float sM = aM * __builtin_fmaf(0.0170329670329670f, e2, 0.025f);
    if (Vn == -35.0f) { aM = 1.638f; sM = 0.06995f; }
    m = __builtin_fmaf(0.05f, aM, __builtin_fmaf(-sM, m, m)) * rcpf(sM + 1.0f);

    // ---- H gate ----
    float aH = 0.25f * ex2(__builtin_fmaf(-0.12018822013770593f, Vn, -10.816939812393534f));
    float bH = 0.25f * ex2(__builtin_fmaf( 0.12018822013770593f, Vn,   4.086399484682001f));
    float sH = 0.025f * (aH + bH);
    h = __builtin_fmaf(0.05f, aH, __builtin_fmaf(-sH, h, h)) * rcpf(sH + 1.0f);

    // ---- synaptic gate ----
    float sy = __builtin_fmaf(0.025f, zc, 0.0025f);
    y = __builtin_fmaf(0.05f, zc, __builtin_fmaf(-sy, y, y)) * rcp1p_small(sy);

    V = Vn;
    // sigmoid((Vn+20)/3): exp(-(Vn+20)/3) = e1^3 * e^-15 (output-only path)
    float E = (e1 * e1) * e1 * 3.0590232050182579e-7f;
    return rcpf(1.0f + E);
}

__global__ __launch_bounds__(64, 1)
void hh_kernel(const float* __restrict__ z, float* __restrict__ out, int N) {
    const int idx = blockIdx.x * 64 + threadIdx.x;   // 0 .. 2047
    const int bA = idx >> 7;                         // chains A: b in [0,16)
    const int l  = idx & 127;
    const size_t baseA = (size_t)bA * N * 128 + l;
    const size_t baseB = (size_t)(bA + 16) * N * 128 + l;   // chain B: b+16
    const float* zA = z + baseA;
    const float* zB = z + baseB;
    float* oA = out + baseA;
    float* oB = out + baseB;

    float VA = -70.0f, mA = 0.0f, nA = 0.0f, hA = 1.0f, yA = 0.0f;
    float VB = -70.0f, mB = 0.0f, nB = 0.0f, hB = 1.0f, yB = 0.0f;

    // t = 0 outputs
    float s0 = rcpf(1.0f + ex2(__builtin_fmaf(-0.4807528805508243f, -70.0f,
                                              -9.615057611016486f)));
    oA[0] = s0; oB[0] = s0;

    // 4-deep rotating prefetch, two streams
    float a0 = zA[0], a1 = zA[128], a2 = zA[256], a3 = zA[384];
    float b0 = zB[0], b1 = zB[128], b2 = zB[256], b3 = zB[384];
    const float* pA = zA + 512;
    const float* pB = zB + 512;
    float* wA = oA + 128;
    float* wB = oB + 128;
    int t = 1;
    for (; t <= N - 7; t += 4) {
        float na0 = pA[0], nb0 = pB[0];
        float na1 = pA[128], nb1 = pB[128];
        float na2 = pA[256], nb2 = pB[256];
        float na3 = pA[384], nb3 = pB[384];
        pA += 512; pB += 512;
        wA[0]   = hh_step(VA, mA, nA, hA, yA, a0);
        wB[0]   = hh_step(VB, mB, nB, hB, yB, b0);
        wA[128] = hh_step(VA, mA, nA, hA, yA, a1);
        wB[128] = hh_step(VB, mB, nB, hB, yB, b1);
        wA[256] = hh_step(VA, mA, nA, hA, yA, a2);
        wB[256] = hh_step(VB, mB, nB, hB, yB, b2);
        wA[384] = hh_step(VA, mA, nA, hA, yA, a3);
        wB[384] = hh_step(VB, mB, nB, hB, yB, b3);
        wA += 512; wB += 512;
        a0 = na0; a1 = na1; a2 = na2; a3 = na3;
        b0 = nb0; b1 = nb1; b2 = nb2; b3 = nb3;
    }
    for (; t < N; ++t) {
        *wA = hh_step(VA, mA, nA, hA, yA, a0);
        *wB = hh_step(VB, mB, nB, hB, yB, b0);
        wA += 128; wB += 128;
        a0 = a1; a1 = a2; a2 = a3;
        b0 = b1; b1 = b2; b2 = b3;
    }
}

extern "C" void kernel_launch(void* const* d_in, const int* in_sizes, int n_in,
                              void* d_out, int out_size, void* d_ws, size_t ws_size,
                              hipStream_t stream) {
    const float* z = (const float*)d_in[0];
    float* out = (float*)d_out;
    const int B = 32, L = 128;
    const int N = in_sizes[0] / (B * L);             // 2000
    dim3 grid(B * L / (2 * 64)), block(64);          // 2 chains per thread
    hipLaunchKernelGGL(hh_kernel, grid, block, 0, stream, z, out, N);
}

// Round 5
// 707.798 us; speedup vs baseline: 1.1763x; 1.1763x over previous
//
#include <hip/hip_runtime.h>

// Hodgkin-Huxley synaptic network, Crank-Nicolson integration.
// R5: wave-specialized split of each chain across TWO waves (one workgroup):
//   wave A: membrane -> Vn, then H gate + y gate.  Owns V, h, y. Loads z.
//   wave B: N gate + M gate (needs Vn), sigmoid + store. Owns m, n.
// Exchange per step via LDS: A->B: Vn;  B->A: m, n.  2 barriers/step.
// Numerics are IDENTICAL to R3/R4 (same ops, same order) -> absmax must be
// bit-identical (0.01171875). 64 blocks x 128 thr = 128 waves (2/CU).

__device__ __forceinline__ float rcpf(float x) { return __builtin_amdgcn_rcpf(x); }
__device__ __forceinline__ float ex2(float x) { return exp2f(x); }
// 1/(1+s) for small s: err ~ s^4
__device__ __forceinline__ float rcp1p_small(float s) {
    float a = 1.0f - s;
    float b = __builtin_fmaf(-s, a, 1.0f);
    return __builtin_fmaf(-s, b, 1.0f);
}

// Wave-A step: membrane from (V, mP, nP, h, y), publish Vn, then H & y gates,
// then pick up B's m,n for the next step. Contains the step's 2 barriers.
__device__ __forceinline__ void stepA(float& V, float& h, float& y,
                                      float& mP, float& nP, float zc,
                                      volatile float* VnS, volatile float* mS,
                                      volatile float* nS, int l) {
    // ---- membrane ----  (GNA*DT/2 == 1 exactly)
    float m2 = mP * mP, mh = mP * h;
    float p1 = m2 * mh;                          // m^3 h
    float n2 = nP * nP, n4 = n2 * n2;
    float gy = __builtin_fmaf(0.0125f, y, 0.0025f);
    float pg = p1 + gy;
    float G  = __builtin_fmaf(0.875f, n4, pg);
    float rd = rcpf(G + 1.0f);
    float t1 = __builtin_fmaf(110.0f, p1, V - 0.3f);
    float t2 = __builtin_fmaf(-134.75f, n4, t1);
    float num = __builtin_fmaf(-V, G, t2);       // V*(1-G) + DT*(E+IAPP)
    float Vn = num * rd;
    VnS[l] = Vn;
    __syncthreads();                             // bar1: Vn visible to B
    // ---- H gate ----
    float aH = 0.25f * ex2(__builtin_fmaf(-0.12018822013770593f, Vn, -10.816939812393534f));
    float bH = 0.25f * ex2(__builtin_fmaf( 0.12018822013770593f, Vn,   4.086399484682001f));
    float sH = 0.025f * (aH + bH);
    h = __builtin_fmaf(0.05f, aH, __builtin_fmaf(-sH, h, h)) * rcpf(sH + 1.0f);
    // ---- synaptic gate ----
    float sy = __builtin_fmaf(0.025f, zc, 0.0025f);
    y = __builtin_fmaf(0.05f, zc, __builtin_fmaf(-sy, y, y)) * rcp1p_small(sy);
    V = Vn;
    __syncthreads();                             // bar2: B's m,n visible to A
    mP = mS[l]; nP = nS[l];
}

__global__ __launch_bounds__(128, 1)
void hh_kernel(const float* __restrict__ z, float* __restrict__ out, int N) {
    __shared__ float VnS[64], mS[64], nS[64];
    const int l  = threadIdx.x & 63;
    const int wv = threadIdx.x >> 6;
    const int chain = blockIdx.x * 64 + l;       // 64 chains per block
    const int b  = chain >> 7;
    const int ll = chain & 127;
    const size_t base = (size_t)b * (size_t)N * 128 + ll;

    if (wv == 0) {
        // ---------------- wave A ----------------
        const float* zp = z + base;
        float V = -70.0f, h = 1.0f, y = 0.0f;
        float mP = 0.0f, nP = 0.0f;              // first step uses m0=0, n0=0
        float z0 = zp[0], z1 = zp[128], z2 = zp[256], z3 = zp[384];
        const float* pz = zp + 512;
        int t = 1;
        for (; t <= N - 7; t += 4) {             // prefetch t+3..t+6 <= N-1
            float p0 = pz[0], p1 = pz[128], p2 = pz[256], p3 = pz[384];
            pz += 512;
            stepA(V, h, y, mP, nP, z0, VnS, mS, nS, l);
            stepA(V, h, y, mP, nP, z1, VnS, mS, nS, l);
            stepA(V, h, y, mP, nP, z2, VnS, mS, nS, l);
            stepA(V, h, y, mP, nP, z3, VnS, mS, nS, l);
            z0 = p0; z1 = p1; z2 = p2; z3 = p3;
        }
        for (; t < N; ++t) {                     // tail (<=6 steps)
            stepA(V, h, y, mP, nP, z0, VnS, mS, nS, l);
            z0 = z1; z1 = z2; z2 = z3;
        }
    } else {
        // ---------------- wave B ----------------
        float* op = out + base;
        float m = 0.0f, n = 0.0f;
        // t = 0 output (V0 = -70)
        op[0] = rcpf(1.0f + ex2(__builtin_fmaf(-0.4807528805508243f, -70.0f,
                                               -9.615057611016486f)));
        float* o = op + 128;
        for (int t = 1; t < N; ++t) {
            __syncthreads();                     // bar1: Vn ready
            float Vn = VnS[l];
            // ---- N gate ----
            float e1 = ex2(__builtin_fmaf(-0.16025096018360795f, Vn, 4.006274004590199f));
            float r1 = rcpf(1.0f - e1);
            float aN = __builtin_fmaf(0.02f, Vn, -0.5f) * r1;
            float sN = aN * __builtin_fmaf(0.0025f, e1, 0.025f);
            if (Vn == 25.0f) { aN = 0.18f; sN = 0.0065f; }
            n = __builtin_fmaf(0.05f, aN, __builtin_fmaf(-sN, n, n)) * rcp1p_small(sN);
            // ---- M gate ----
            float e2 = ex2(__builtin_fmaf(-0.16025096018360795f, Vn, -5.608783606426278f));
            float r2 = rcpf(1.0f - e2);
            float aM = __builtin_fmaf(0.182f, Vn, 6.37f) * r2;
            float sM = aM * __builtin_fmaf(0.0170329670329670f, e2, 0.025f);
            if (Vn == -35.0f) { aM = 1.638f; sM = 0.06995f; }
            m = __builtin_fmaf(0.05f, aM, __builtin_fmaf(-sM, m, m)) * rcpf(sM + 1.0f);
            mS[l] = m; nS[l] = n;
            __syncthreads();                     // bar2: m,n handed to A
            // sigmoid + store AFTER bar2: overlaps A's next membrane phase.
            // exp(-(Vn+20)/3) = e1^3 * e^-15
            float E = (e1 * e1) * e1 * 3.0590232050182579e-7f;
            *o = rcpf(1.0f + E);
            o += 128;
        }
    }
}

extern "C" void kernel_launch(void* const* d_in, const int* in_sizes, int n_in,
                              void* d_out, int out_size, void* d_ws, size_t ws_size,
                              hipStream_t stream) {
    const float* z = (const float*)d_in[0];
    float* out = (float*)d_out;
    const int B = 32, L = 128;
    const int N = in_sizes[0] / (B * L);         // 2000
    dim3 grid(B * L / 64), block(128);           // 64 blocks x 2 waves
    hipLaunchKernelGGL(hh_kernel, grid, block, 0, stream, z, out, N);
}

// Round 6
// 345.373 us; speedup vs baseline: 2.4108x; 2.0494x over previous
//
#include <hip/hip_runtime.h>

// Hodgkin-Huxley synaptic network, Crank-Nicolson integration.
// R6: R3 shape (1 chain/thread, 64 waves, 4-deep z prefetch) + trans diet:
//   - sigmoid moved to a second, massively-parallel pass (store raw Vn)
//   - e2 = e1 * exp(-60/9)        (exact algebra, -1 exp)
//   - 1/((1+sM)(1+sH)) fused rcp  (both >= 1, safe, -1 rcp)
//   - Neumann series for 1/(1+sN), 1/(1+sy)  (s <= 0.028)
//   - exp2 constants corrected to full precision (R3-R5's were 3e-4 low:
//     0.16025096 vs true 1/(9 ln2) = 0.16029945 -- absmax regression source)
// Serial step: 3 exp + 4 rcp (R3 had 5 exp + 8 rcp).

__device__ __forceinline__ float rcpf(float x) { return __builtin_amdgcn_rcpf(x); }
__device__ __forceinline__ float ex2(float x) { return exp2f(x); }
// 1/(1+s) for small s: 1 - s + s^2 - s^3, err ~ s^4 (s <= 0.028 -> <= 6e-7)
__device__ __forceinline__ float rcp1p_small(float s) {
    float a = 1.0f - s;
    float b = __builtin_fmaf(-s, a, 1.0f);
    return __builtin_fmaf(-s, b, 1.0f);
}

// Constants (exp2 domain), full precision:
//   C9  = 1/(9 ln2)  = 0.16029944941   25*C9 = 4.00748623525
//   C12 = 1/(12 ln2) = 0.12022458393  -90*C12 = -10.820212554  34*C12 = 4.0876358536
//   C3  = 1/(3 ln2)  = 0.48089834664  -20*C3 = -9.6179669328
//   E2C = exp(-60/9) = 1.2726338e-3

// One CN step; stores/returns raw Vn (sigmoid applied by pass 2).
__device__ __forceinline__ float hh_step(float& V, float& m, float& n, float& h,
                                         float& y, float zc) {
    // ---- membrane ----  (GNA*DT/2 == 1 exactly)
    float m2 = m * m, mh = m * h;
    float p1 = m2 * mh;                          // m^3 h
    float n2 = n * n, n4 = n2 * n2;
    float gy = __builtin_fmaf(0.0125f, y, 0.0025f);
    float pg = p1 + gy;
    float G  = __builtin_fmaf(0.875f, n4, pg);
    float rd = rcpf(G + 1.0f);
    float t1 = __builtin_fmaf(110.0f, p1, V - 0.3f);
    float t2 = __builtin_fmaf(-134.75f, n4, t1);
    float num = __builtin_fmaf(-V, G, t2);       // V*(1-G) + DT*(E+IAPP)
    float Vn = num * rd;

    // ---- N & M rates ----  e1 = exp((25-Vn)/9);  e2 = exp((-35-Vn)/9) = e1*E2C
    float e1 = ex2(__builtin_fmaf(-0.16029944941f, Vn, 4.00748623525f));
    float e2 = e1 * 1.2726338e-3f;
    float r1 = rcpf(1.0f - e1);
    float r2 = rcpf(1.0f - e2);
    float aN = __builtin_fmaf(0.02f, Vn, -0.5f) * r1;
    float aM = __builtin_fmaf(0.182f, Vn, 6.37f) * r2;
    float sN = aN * __builtin_fmaf(0.0025f, e1, 0.025f);          // 0.025*(aN+bN)
    float sM = aM * __builtin_fmaf(0.0170329670329670f, e2, 0.025f);
    if (Vn == 25.0f)  { aN = 0.18f;  sN = 0.0065f;  }             // 0.025*(0.18+0.08)
    if (Vn == -35.0f) { aM = 1.638f; sM = 0.06995f; }             // 0.025*(1.638+1.16)

    // ---- H rates ----
    float aH = 0.25f * ex2(__builtin_fmaf(-0.12022458393f, Vn, -10.820212554f));
    float bH = 0.25f * ex2(__builtin_fmaf( 0.12022458393f, Vn,   4.0876358536f));
    float sH = 0.025f * (aH + bH);

    // ---- gate updates ----
    n = __builtin_fmaf(0.05f, aN, __builtin_fmaf(-sN, n, n)) * rcp1p_small(sN);
    float dM = sM + 1.0f, dH = sH + 1.0f;
    float rMH = rcpf(dM * dH);                   // fused: 1/((1+sM)(1+sH))
    m = __builtin_fmaf(0.05f, aM, __builtin_fmaf(-sM, m, m)) * (dH * rMH);
    h = __builtin_fmaf(0.05f, aH, __builtin_fmaf(-sH, h, h)) * (dM * rMH);

    // ---- synaptic gate ----
    float sy = __builtin_fmaf(0.025f, zc, 0.0025f);
    y = __builtin_fmaf(0.05f, zc, __builtin_fmaf(-sy, y, y)) * rcp1p_small(sy);

    V = Vn;
    return Vn;
}

__global__ __launch_bounds__(64, 1)
void hh_kernel(const float* __restrict__ z, float* __restrict__ out, int N) {
    const int idx = blockIdx.x * 64 + threadIdx.x;   // 0 .. B*L-1
    const int b = idx >> 7;
    const int l = idx & 127;
    const size_t base = (size_t)b * N * 128 + l;
    const float* zp = z + base;
    float* op = out + base;

    float V = -70.0f, m = 0.0f, n = 0.0f, h = 1.0f, y = 0.0f;

    op[0] = -70.0f;                              // raw V0; pass 2 sigmoids it

    // 4-deep rotating prefetch
    float z0 = zp[0], z1 = zp[128], z2 = zp[256], z3 = zp[384];
    const float* zpre = zp + 512;
    float* o = op + 128;
    int t = 1;
    for (; t <= N - 7; t += 4) {                 // prefetch t+3..t+6 <= N-1
        float p0 = zpre[0];
        float p1 = zpre[128];
        float p2 = zpre[256];
        float p3 = zpre[384];
        zpre += 512;
        o[0]   = hh_step(V, m, n, h, y, z0);
        o[128] = hh_step(V, m, n, h, y, z1);
        o[256] = hh_step(V, m, n, h, y, z2);
        o[384] = hh_step(V, m, n, h, y, z3);
        o += 512;
        z0 = p0; z1 = p1; z2 = p2; z3 = p3;
    }
    for (; t < N; ++t) {                         // tail (<=6 steps)
        *o = hh_step(V, m, n, h, y, z0);
        o += 128;
        z0 = z1; z1 = z2; z2 = z3;
    }
}

// Pass 2: in-place sigmoid((v - VT)/KP) over the whole output, float4.
__global__ __launch_bounds__(256)
void sig_kernel(float4* __restrict__ v, int n4) {
    int i = blockIdx.x * 256 + threadIdx.x;
    if (i < n4) {
        float4 x = v[i];
        x.x = rcpf(1.0f + ex2(__builtin_fmaf(-0.48089834664f, x.x, -9.6179669328f)));
        x.y = rcpf(1.0f + ex2(__builtin_fmaf(-0.48089834664f, x.y, -9.6179669328f)));
        x.z = rcpf(1.0f + ex2(__builtin_fmaf(-0.48089834664f, x.z, -9.6179669328f)));
        x.w = rcpf(1.0f + ex2(__builtin_fmaf(-0.48089834664f, x.w, -9.6179669328f)));
        v[i] = x;
    }
}

extern "C" void kernel_launch(void* const* d_in, const int* in_sizes, int n_in,
                              void* d_out, int out_size, void* d_ws, size_t ws_size,
                              hipStream_t stream) {
    const float* z = (const float*)d_in[0];
    float* out = (float*)d_out;
    const int B = 32, L = 128;
    const int N = in_sizes[0] / (B * L);             // 2000
    dim3 grid(B * L / 64), block(64);
    hipLaunchKernelGGL(hh_kernel, grid, block, 0, stream, z, out, N);
    const int n4 = out_size / 4;                     // out_size divisible by 4
    dim3 sgrid((n4 + 255) / 256), sblock(256);
    hipLaunchKernelGGL(sig_kernel, sgrid, sblock, 0, stream, (float4*)out, n4);
}

// Round 7
// 281.995 us; speedup vs baseline: 2.9526x; 1.2247x over previous
//
#include <hip/hip_runtime.h>

// Hodgkin-Huxley synaptic network, Crank-Nicolson integration.
// R7: R6 structure (1 chain/thread, 64 waves, 4-deep z prefetch, separate
// sigmoid pass) + issue-count/scheduling attack:
//   - raw v_exp_f32 via __builtin_amdgcn_exp2f (args in [-32,21]: no denormal
//     path -> bit-identical to exp2f, minus the ocml wrapper instructions)
//   - fused N/M rate rcp: R = rcp((1-e1)(1-e2))        (-1 trans)
//   - H-gate scalings folded: sH = 0.00625*(E3+E4), h-num uses 0.0125*E3
//   - y-gate hoisted into membrane-rcp latency shadow; next step's
//     p1 = m^3 h and n4 computed at end of step (fills post-rcp bubbles)
// Serial step: 3 exp + 3 rcp + 2 Neumann.

#if __has_builtin(__builtin_amdgcn_exp2f)
#define EXP2 __builtin_amdgcn_exp2f
#else
#define EXP2 exp2f
#endif

__device__ __forceinline__ float rcpf(float x) { return __builtin_amdgcn_rcpf(x); }
// 1/(1+s) for small s: 1 - s + s^2 - s^3, err ~ s^4 (s <= 0.028 -> <= 6e-7)
__device__ __forceinline__ float rcp1p_small(float s) {
    float a = 1.0f - s;
    float b = __builtin_fmaf(-s, a, 1.0f);
    return __builtin_fmaf(-s, b, 1.0f);
}

// exp2-domain constants (full precision):
//   C9  = 1/(9 ln2)  = 0.16029944941   25*C9 = 4.00748623525
//   C12 = 1/(12 ln2) = 0.12022458393  -90*C12 = -10.820212554  34*C12 = 4.0876358536
//   C3  = 1/(3 ln2)  = 0.48089834664  -20*C3 = -9.6179669328
//   E2C = exp(-60/9) = 1.2726338e-3

// One CN step. p1 = m^3*h and n4 = n^4 are carried state (computed at the
// end of the previous step). Returns raw Vn (sigmoid applied in pass 2).
__device__ __forceinline__ float hh_step(float& V, float& m, float& n, float& h,
                                         float& y, float& p1, float& n4, float zc) {
    // ---- membrane ----  (GNA*DT/2 == 1 exactly)
    float gy = __builtin_fmaf(0.0125f, y, 0.0025f);
    float pg = p1 + gy;
    float G  = __builtin_fmaf(0.875f, n4, pg);
    float rd = rcpf(G + 1.0f);
    // y-gate: z-driven, independent of Vn -- fills rd's latency window
    float sy = __builtin_fmaf(0.025f, zc, 0.0025f);
    float yn = __builtin_fmaf(0.05f, zc, __builtin_fmaf(-sy, y, y)) * rcp1p_small(sy);
    float t1 = __builtin_fmaf(110.0f, p1, V - 0.3f);
    float t2 = __builtin_fmaf(-134.75f, n4, t1);
    float Vn = __builtin_fmaf(-V, G, t2) * rd;     // (V(1-G)+DT(E+IAPP))/(1+G)

    // ---- all 3 exps issued ASAP after Vn ----
    float e1 = EXP2(__builtin_fmaf(-0.16029944941f, Vn, 4.00748623525f));
    float E3 = EXP2(__builtin_fmaf(-0.12022458393f, Vn, -10.820212554f));
    float E4 = EXP2(__builtin_fmaf( 0.12022458393f, Vn,   4.0876358536f));

    // ---- N & M rates ----  e2 = e1 * exp(-60/9)
    float e2 = e1 * 1.2726338e-3f;
    float u1 = 1.0f - e1, u2 = 1.0f - e2;
    float R  = rcpf(u1 * u2);                      // fused rcp for both rates
    float aN = __builtin_fmaf(0.02f, Vn, -0.5f) * (u2 * R);
    float aM = __builtin_fmaf(0.182f, Vn, 6.37f) * (u1 * R);
    float sN = aN * __builtin_fmaf(0.0025f, e1, 0.025f);          // 0.025*(aN+bN)
    float sM = aM * __builtin_fmaf(0.0170329670329670f, e2, 0.025f);
    if (Vn == 25.0f)  { aN = 0.18f;  sN = 0.0065f;  }
    if (Vn == -35.0f) { aM = 1.638f; sM = 0.06995f; }

    // ---- H rates (scalings folded) ----
    float sH = 0.00625f * (E3 + E4);               // 0.025*(0.25E3+0.25E4)

    // ---- gate updates ----
    float dM = sM + 1.0f, dH = sH + 1.0f;
    float rMH = rcpf(dM * dH);                     // fused 1/((1+sM)(1+sH))
    float nn = __builtin_fmaf(0.05f, aN, __builtin_fmaf(-sN, n, n)) * rcp1p_small(sN);
    float mn = __builtin_fmaf(0.05f, aM, __builtin_fmaf(-sM, m, m)) * (dH * rMH);
    float hn = __builtin_fmaf(0.0125f, E3, __builtin_fmaf(-sH, h, h)) * (dM * rMH);

    m = mn; n = nn; h = hn; y = yn; V = Vn;
    // next step's powers: issue now to fill the post-rcp/store window
    float m2 = mn * mn, mh = mn * hn;
    p1 = m2 * mh;                                  // m^3 h
    float q  = nn * nn;
    n4 = q * q;                                    // n^4
    return Vn;
}

__global__ __launch_bounds__(64, 1)
void hh_kernel(const float* __restrict__ z, float* __restrict__ out, int N) {
    const int idx = blockIdx.x * 64 + threadIdx.x;   // 0 .. B*L-1
    const int b = idx >> 7;
    const int l = idx & 127;
    const size_t base = (size_t)b * N * 128 + l;
    const float* zp = z + base;
    float* op = out + base;

    float V = -70.0f, m = 0.0f, n = 0.0f, h = 1.0f, y = 0.0f;
    float p1 = 0.0f, n4 = 0.0f;                  // m^3 h = 0, n^4 = 0 initially

    op[0] = -70.0f;                              // raw V0; pass 2 sigmoids it

    // 4-deep rotating prefetch: z0..z3 = z[t-1..t+2]
    float z0 = zp[0], z1 = zp[128], z2 = zp[256], z3 = zp[384];
    const float* zpre = zp + 512;                // next load: z[t+3]
    float* o = op + 128;
    int t = 1;
    for (; t <= N - 7; t += 4) {                 // prefetch t+3..t+6 <= N-1
        float q0 = zpre[0];
        float q1 = zpre[128];
        float q2 = zpre[256];
        float q3 = zpre[384];
        zpre += 512;
        o[0]   = hh_step(V, m, n, h, y, p1, n4, z0);
        o[128] = hh_step(V, m, n, h, y, p1, n4, z1);
        o[256] = hh_step(V, m, n, h, y, p1, n4, z2);
        o[384] = hh_step(V, m, n, h, y, p1, n4, z3);
        o += 512;
        z0 = q0; z1 = q1; z2 = q2; z3 = q3;
    }
    for (; t < N; ++t) {                         // robust tail (any length)
        *o = hh_step(V, m, n, h, y, p1, n4, z0);
        o += 128;
        z0 = z1; z1 = z2; z2 = z3;
        z3 = (t + 3 <= N - 1) ? zpre[0] : 0.0f;
        zpre += 128;
    }
}

// Pass 2: in-place sigmoid((v - VT)/KP) over the whole output, float4.
__global__ __launch_bounds__(256)
void sig_kernel(float4* __restrict__ v, int n4c) {
    int i = blockIdx.x * 256 + threadIdx.x;
    if (i < n4c) {
        float4 x = v[i];
        x.x = rcpf(1.0f + EXP2(__builtin_fmaf(-0.48089834664f, x.x, -9.6179669328f)));
        x.y = rcpf(1.0f + EXP2(__builtin_fmaf(-0.48089834664f, x.y, -9.6179669328f)));
        x.z = rcpf(1.0f + EXP2(__builtin_fmaf(-0.48089834664f, x.z, -9.6179669328f)));
        x.w = rcpf(1.0f + EXP2(__builtin_fmaf(-0.48089834664f, x.w, -9.6179669328f)));
        v[i] = x;
    }
}

extern "C" void kernel_launch(void* const* d_in, const int* in_sizes, int n_in,
                              void* d_out, int out_size, void* d_ws, size_t ws_size,
                              hipStream_t stream) {
    const float* z = (const float*)d_in[0];
    float* out = (float*)d_out;
    const int B = 32, L = 128;
    const int N = in_sizes[0] / (B * L);             // 2000
    dim3 grid(B * L / 64), block(64);
    hipLaunchKernelGGL(hh_kernel, grid, block, 0, stream, z, out, N);
    const int n4c = out_size / 4;                    // out_size divisible by 4
    dim3 sgrid((n4c + 255) / 256), sblock(256);
    hipLaunchKernelGGL(sig_kernel, sgrid, sblock, 0, stream, (float4*)out, n4c);
}

// Round 9
// 245.595 us; speedup vs baseline: 3.3902x; 1.1482x over previous
//
#include <hip/hip_runtime.h>

// Hodgkin-Huxley synaptic network, Crank-Nicolson integration.
// R9 = R8 with the host-pass compile fix (DPP guarded by __HIP_DEVICE_COMPILE__).
// FOUR LANES PER CHAIN, gate-parallel. Lanes of a quad split the step:
//   lane0: N gate (e1)   lane1: M gate (e2)   lane2: H gate (E3)   lane3: y gate (E4)
// All gates share one algebraic form with per-lane CONSTANTS (VGPRs, no
// divergence). Membrane is computed redundantly in all 4 lanes from
// quad-broadcast gate values (4x v_mov_dpp, VALU-speed, no LDS/barrier).
// 16384 threads = 256 waves (1/CU chip-wide). 8-deep z prefetch.
// Numerics: identical formulas to R7 (per-gate rcp, direct e2 exp) -> absmax
// expected ~0.0039. Singularity fixups kept (sing=NaN on lanes 2,3).

#if defined(__HIP_DEVICE_COMPILE__)
#define EXP2 __builtin_amdgcn_exp2f
#else
#define EXP2 exp2f
#endif

__device__ __forceinline__ float rcpf(float x) { return __builtin_amdgcn_rcpf(x); }

template<int CTRL>
__device__ __forceinline__ float qp(float x) {
#if defined(__HIP_DEVICE_COMPILE__)
    return __int_as_float(__builtin_amdgcn_mov_dpp(__float_as_int(x), CTRL, 0xF, 0xF, false));
#else
    return x;   // host pass: never executed, just needs to type-check
#endif
}
#define QB0(x) qp<0x00>(x)   // quad_perm broadcast lane 0
#define QB1(x) qp<0x55>(x)   // broadcast lane 1
#define QB2(x) qp<0xAA>(x)   // broadcast lane 2
#define QB3(x) qp<0xFF>(x)   // broadcast lane 3
#define QSW(x) qp<0xB1>(x)   // quad_perm[1,0,3,2]: lane^1 swap

struct LaneC {
    float cA, cB, cC, cD, cE, cW, cV, cZ, cH, cX, cY, sing, fixA, fixS;
};

// One CN step for a 4-lane quad. g = this lane's gate (n/m/h/y). Returns Vn.
__device__ __forceinline__ float hh_step4(float& V, float& g, float z,
                                          const LaneC& C, bool is23) {
    // gather gate values (quad broadcasts, VALU-speed)
    float nn = QB0(g), mm = QB1(g), hh = QB2(g), yy = QB3(g);
    // ---- membrane (redundant in all 4 lanes; bit-identical across quad) ----
    float m2 = mm * mm, mh = mm * hh;
    float p1 = m2 * mh;                              // m^3 h  (GNA*DT/2 == 1)
    float q  = nn * nn, n4 = q * q;
    float gy = __builtin_fmaf(0.0125f, yy, 0.0025f);
    float pg = p1 + gy;
    float G  = __builtin_fmaf(0.875f, n4, pg);
    float rd = rcpf(G + 1.0f);
    float t1 = __builtin_fmaf(110.0f, p1, V - 0.3f);
    float t2 = __builtin_fmaf(-134.75f, n4, t1);
    float Vn = __builtin_fmaf(-V, G, t2) * rd;       // (V(1-G)+DT(E+IAPP))/(1+G)
    // ---- this lane's gate ----
    float E  = EXP2(__builtin_fmaf(C.cA, Vn, C.cB));
    float t  = __builtin_fmaf(C.cC, Vn, C.cD);
    float u  = rcpf(__builtin_fmaf(-C.cE, E, 1.0f)); // rcp(1-e) (lanes 2,3: rcp(1)=1)
    float w  = C.cW * E;                             // 0.25*E on lanes 2,3; 0 else
    float a  = __builtin_fmaf(t, u, __builtin_fmaf(C.cV, w, C.cZ * z));
    float br = QSW(w);                               // lane2 <- lane3's 0.25*E4
    float b  = __builtin_fmaf(C.cX, br, C.cY);       // lane3: 0.1 const
    float s1 = a * __builtin_fmaf(C.cH, E, 0.025f);  // N/M: 0.025*(a+b) factored
    float s2 = 0.025f * (a + b);                     // H: 0.025(aH+bH); y: 0.025(z+0.1)
    float s  = is23 ? s2 : s1;
    bool fx  = (Vn == C.sing);                       // NaN on lanes 2,3 -> false
    a = fx ? C.fixA : a;
    s = fx ? C.fixS : s;
    float r  = rcpf(s + 1.0f);
    g = __builtin_fmaf(0.05f, a, __builtin_fmaf(-s, g, g)) * r;
    V = Vn;
    return Vn;
}

__global__ __launch_bounds__(64, 1)
void hh_kernel(const float* __restrict__ z, float* __restrict__ out, int N) {
    const int gid   = blockIdx.x * 64 + threadIdx.x; // 0 .. 16383
    const int lane  = gid & 3;
    const int chain = gid >> 2;                      // 0 .. 4095
    const int b = chain >> 7;
    const int l = chain & 127;
    const size_t base = (size_t)b * N * 128 + l;
    const float* zp = z + base;
    float* op = out + base;
    const bool is0  = (lane == 0);
    const bool is23 = (lane & 2) != 0;

    // per-lane gate constants (exp2-domain; C9=1/(9ln2), C12=1/(12ln2))
    LaneC C;
    const float NaNf = __int_as_float(0x7FC00000);
    switch (lane) {
    case 0:  // N gate: e1 = exp((25-Vn)/9)
        C = { -0.1602994490f,  4.0074862250f, 0.02f, -0.5f, 1.0f, 0.0f, 0.0f, 0.0f,
              0.0025f, 0.0f, 0.0f, 25.0f, 0.18f, 0.0065f };
        break;
    case 1:  // M gate: e2 = exp((-35-Vn)/9)
        C = { -0.1602994490f, -5.6104807150f, 0.182f, 6.37f, 1.0f, 0.0f, 0.0f, 0.0f,
              0.0170329670329670f, 0.0f, 0.0f, -35.0f, 1.638f, 0.06995f };
        break;
    case 2:  // H gate: E3 = exp((-90-Vn)/12); aH = 0.25*E3; bH from lane3's E4
        C = { -0.1202245839f, -10.8202125510f, 0.0f, 0.0f, 0.0f, 0.25f, 1.0f, 0.0f,
              0.0f, 1.0f, 0.0f, NaNf, 0.0f, 0.0f };
        break;
    default: // y gate: E4 = exp((Vn+34)/12) (feeds lane2's bH); a = z
        C = {  0.1202245839f,   4.0876358530f, 0.0f, 0.0f, 0.0f, 0.25f, 0.0f, 1.0f,
              0.0f, 0.0f, 0.1f, NaNf, 0.0f, 0.0f };
        break;
    }

    float V = -70.0f;
    float g = (lane == 2) ? 1.0f : 0.0f;             // n=0, m=0, h=1, y=0

    if (is0) op[0] = -70.0f;                         // raw V0; pass 2 sigmoids it

    // 8-deep rotating prefetch: z0..z7 = z[t-1 .. t+6]
    float z0 = (0 <= N-2) ? zp[0]     : 0.0f;
    float z1 = (1 <= N-2) ? zp[128]   : 0.0f;
    float z2 = (2 <= N-2) ? zp[256]   : 0.0f;
    float z3 = (3 <= N-2) ? zp[384]   : 0.0f;
    float z4 = (4 <= N-2) ? zp[512]   : 0.0f;
    float z5 = (5 <= N-2) ? zp[640]   : 0.0f;
    float z6 = (6 <= N-2) ? zp[768]   : 0.0f;
    float z7 = (7 <= N-2) ? zp[896]   : 0.0f;
    const float* zpre = zp + 8 * 128;                // next load: z[t+7] at t=1
    float* o = op + 128;
    int t = 1;
    // main: loads touch z indices t+7..t+10 <= N-1  ->  t <= N-11
    for (; t <= N - 11; t += 4) {
        float q0 = zpre[0];
        float q1 = zpre[128];
        float q2 = zpre[256];
        float q3 = zpre[384];
        zpre += 512;
        float v0 = hh_step4(V, g, z0, C, is23);
        float v1 = hh_step4(V, g, z1, C, is23);
        float v2 = hh_step4(V, g, z2, C, is23);
        float v3 = hh_step4(V, g, z3, C, is23);
        if (is0) { o[0] = v0; o[128] = v1; o[256] = v2; o[384] = v3; }
        o += 512;
        z0 = z4; z1 = z5; z2 = z6; z3 = z7;
        z4 = q0; z5 = q1; z6 = q2; z7 = q3;
    }
    // tail: per-step shift; refill z7 while in range
    for (; t < N; ++t) {
        float v0 = hh_step4(V, g, z0, C, is23);
        if (is0) *o = v0;
        o += 128;
        z0 = z1; z1 = z2; z2 = z3; z3 = z4; z4 = z5; z5 = z6; z6 = z7;
        z7 = (t + 7 <= N - 1) ? zpre[0] : 0.0f;      // z[t+7] for step t+8
        zpre += 128;
    }
}

// Pass 2: in-place sigmoid((v - VT)/KP) over the whole output, float4.
__global__ __launch_bounds__(256)
void sig_kernel(float4* __restrict__ v, int n4c) {
    int i = blockIdx.x * 256 + threadIdx.x;
    if (i < n4c) {
        float4 x = v[i];
        x.x = rcpf(1.0f + EXP2(__builtin_fmaf(-0.48089834664f, x.x, -9.6179669328f)));
        x.y = rcpf(1.0f + EXP2(__builtin_fmaf(-0.48089834664f, x.y, -9.6179669328f)));
        x.z = rcpf(1.0f + EXP2(__builtin_fmaf(-0.48089834664f, x.z, -9.6179669328f)));
        x.w = rcpf(1.0f + EXP2(__builtin_fmaf(-0.48089834664f, x.w, -9.6179669328f)));
        v[i] = x;
    }
}

extern "C" void kernel_launch(void* const* d_in, const int* in_sizes, int n_in,
                              void* d_out, int out_size, void* d_ws, size_t ws_size,
                              hipStream_t stream) {
    const float* z = (const float*)d_in[0];
    float* out = (float*)d_out;
    const int B = 32, L = 128;
    const int N = in_sizes[0] / (B * L);             // 2000
    dim3 grid(B * L * 4 / 64), block(64);            // 4 lanes/chain -> 256 waves
    hipLaunchKernelGGL(hh_kernel, grid, block, 0, stream, z, out, N);
    const int n4c = out_size / 4;                    // out_size divisible by 4
    dim3 sgrid((n4c + 255) / 256), sblock(256);
    hipLaunchKernelGGL(sig_kernel, sgrid, sblock, 0, stream, (float4*)out, n4c);
}